// Round 2
// baseline (82.858 us; speedup 1.0000x reference)
//
#include <hip/hip_runtime.h>
#include <hip/hip_fp16.h>
#include <cstdint>

// Problem constants
#define BB   4
#define IH   64
#define IW   64
#define HWN  4096
#define NVN  16
#define NSN  16

// dtypes (established R1-R3): all inputs f32, output f32.
//
// R5 post-mortem: 82.7us = ~63us fixed harness ws-fills + ~19.5us kernels.
// R6 changes (address-arithmetic driven):
//   1. C/E LDS row stride 48 -> 49 units: 48u = 192 words === 0 mod 32 meant
//      every o-row hit the same bank phase -> ~8-way conflicts across the 4
//      random pixel-groups per wave. 49u = 196 === 4 mod 32 rotates rows.
//   2. Coalesced stores via 4.3KB LDS staging: nv-in-lane layout made each
//      store inst 64 scattered 4B transactions; re-map (pg in low lanes)
//      after an LDS round-trip -> 64B-contiguous segments.
//   3. Transpose: 512 blocks (2/CU) + float4 global reads.
// R7-R8: identical resubmits — R0/R1 benches failed on GPU acquisition
//   (broker at capacity; no counters). Baseline re-establishment pending.
// Math identical to the verified separable factorization:
//   pred[j] = sum_taps (wy-blend E rows) . ((wx-blend C rows) . lgn4)

// ws layout (16B-aligned offsets):
//   lgnT f16 [b][hw][64ch]          : 4*4096*64*2  = 2 MiB
//   Ews  f16 [b][nv][n][j*4+k2]     : 4*16*16*16*2 = 32 KiB
//   Cws  f16 [nv][o][k2*4+l]        : 16*16*16*2   = 8 KiB
#define EWS_OFF  (BB*HWN*64*2)
#define CWS_OFF  (EWS_OFF + BB*NVN*NSN*16*2)

struct __align__(16) H2x4 { __half2 h[4]; };
struct __align__(8)  H2x2 { __half2 a, b; };

__global__ __launch_bounds__(256) void prep_kernel(
    const float* __restrict__ lgn, const float* __restrict__ theta,
    const float* __restrict__ coefx, const float* __restrict__ coefy,
    const float* __restrict__ coefr, char* __restrict__ ws)
{
    const int blk = blockIdx.x, t = threadIdx.x;
    if (blk < 512) {
        // transpose lgn [b][c][hw] f32 -> lgnT [b][hw][c] f16 (32-pixel tiles)
        __shared__ float tile[64][33];   // stride 33: pack-read 2-way max
        const int b      = blk >> 7;
        const int hwbase = (blk & 127) << 5;
        const float* src = lgn + (size_t)b * (64 * HWN) + hwbase;
        const int x4 = t & 7;        // float4 col: 8 x 16B = 32 floats
        const int c0 = t >> 3;       // 32 rows per iter
        #pragma unroll
        for (int i = 0; i < 2; ++i) {
            const int c = c0 + i * 32;
            const float4 v = *(const float4*)&src[c * HWN + x4 * 4];
            tile[c][x4 * 4 + 0] = v.x;
            tile[c][x4 * 4 + 1] = v.y;
            tile[c][x4 * 4 + 2] = v.z;
            tile[c][x4 * 4 + 3] = v.w;
        }
        __syncthreads();
        __half2* dst = (__half2*)ws + (size_t)b * (HWN * 32) + (size_t)hwbase * 32;
        const int cp = t & 31, hw0 = t >> 5;
        #pragma unroll
        for (int i = 0; i < 4; ++i) {
            const int hw = hw0 + i * 8;
            dst[hw * 32 + cp] =
                __floats2half2_rn(tile[2 * cp][hw], tile[2 * cp + 1][hw]);
        }
    } else if (blk < 544) {
        // E[b][nv][n][j*4+k2] = sum_k1 coefx[nv,j,k1,n] *
        //   (wz0*coefy[nv,k1,k2,m0c] + wz1*coefy[nv,k1,k2,m1c]);  half2 pairs
        const int p  = (blk - 512) * 256 + t;        // 8192 half2 pairs
        const int b  = p >> 11, nv = (p >> 7) & 15, n = (p >> 3) & 15, q = p & 7;
        const float th  = theta[b] * 0.31830988618379067154f;   // theta/pi
        const float zf  = (th + 1.0f) * 8.0f - 0.5f;
        const float zfl = floorf(zf);
        const float fz  = zf - zfl;
        const int   m0  = (int)zfl;
        const float wz0 = (m0 >= 0 && m0 <= 15) ? (1.0f - fz) : 0.0f;
        const float wz1 = (m0 + 1 >= 0 && m0 + 1 <= 15) ? fz : 0.0f;
        const int   m0c = min(max(m0, 0), 15), m1c = min(max(m0 + 1, 0), 15);
        float ev[2];
        #pragma unroll
        for (int s = 0; s < 2; ++s) {
            const int idx = 2 * q + s, j = idx >> 2, k2 = idx & 3;
            float e = 0.0f;
            #pragma unroll
            for (int k1 = 0; k1 < 4; ++k1) {
                const float a  = coefx[nv * 256 + (j * 4 + k1) * 16 + n];
                const float bm = wz0 * coefy[nv * 256 + (k1 * 4 + k2) * 16 + m0c]
                               + wz1 * coefy[nv * 256 + (k1 * 4 + k2) * 16 + m1c];
                e += a * bm;
            }
            ev[s] = e;
        }
        ((__half2*)(ws + EWS_OFF))[p] = __floats2half2_rn(ev[0], ev[1]);
    } else {
        // C repack: Cws[nv][o][k2*4+l] = coefr[nv,k2,l,o];  half2 pairs
        const int p = (blk - 544) * 256 + t;          // 2048 half2 pairs
        if (p < 2048) {
            const int nv = p >> 7, o = (p >> 3) & 15, q = p & 7;
            const float c0 = coefr[nv * 256 + (2 * q + 0) * 16 + o];
            const float c1 = coefr[nv * 256 + (2 * q + 1) * 16 + o];
            ((__half2*)(ws + CWS_OFF))[p] = __floats2half2_rn(c0, c1);
        }
    }
}

// LDS layout for C/E: 16B units, unit(nv,o,u) = o*49 + nv*3 + u (u=0,1 data).
// Row stride 49u = 196 words === 4 mod 32 -> rows rotate bank phase.
__global__ __launch_bounds__(256) void seprot_kernel(
    const float* __restrict__ grid1,
    const float* __restrict__ grid2,
    const char*  __restrict__ ws,
    float* __restrict__ out)
{
    __shared__ H2x4 sC[16 * 49];        // 12.25 KiB
    __shared__ H2x4 sE[16 * 49];        // 12.25 KiB
    __shared__ float sOut[16][17][4];   // 4.25 KiB store-coalescing stage

    const int t   = threadIdx.x;
    const int blk = blockIdx.x;
    const int b      = blk >> 8;             // block-uniform
    const int hwbase = (blk & 255) << 4;     // 16 pixels per block
    const int pg = t >> 4;                   // pixel in block (0..15)
    const int nv = t & 15;                   // lane-group = 16 nv of one pixel
    const int hw = hwbase + pg;

    // ---- stage C + E[b] (coalesced copy, padding applied here) ----
    {
        const H2x4* Cw = (const H2x4*)(ws + CWS_OFF);
        const H2x4* Ew = (const H2x4*)(ws + EWS_OFF) + b * 512;
        #pragma unroll
        for (int k = 0; k < 2; ++k) {
            const int i   = t + k * 256;                 // 512 units each
            const int wnv = i >> 5, wo = (i >> 1) & 15, wu = i & 1;
            const int du  = wo * 49 + wnv * 3 + wu;
            sC[du] = Cw[i];
            sE[du] = Ew[i];
        }
    }
    __syncthreads();

    // ---- per-pixel warp geometry (redundant across the 16 nv lanes) ----
    const float2 g2  = ((const float2*)grid2)[b * HWN + hw];
    const float  sxf = rintf((g2.x + 1.0f) * (0.5f * IW) - 0.5f);
    const float  syf = rintf((g2.y + 1.0f) * (0.5f * IH) - 0.5f);
    const bool valid = (sxf >= 0.0f) && (sxf <= (float)(IW - 1)) &&
                       (syf >= 0.0f) && (syf <= (float)(IH - 1));

    float acc[4] = {0.0f, 0.0f, 0.0f, 0.0f};

    if (valid) {
        const int sx = (int)sxf, sy = (int)syf;
        const __half2 zero2 = __floats2half2_rn(0.0f, 0.0f);

        #pragma unroll
        for (int tap = 0; tap < 9; ++tap) {
            const int di = tap / 3 - 1, dj = tap % 3 - 1;
            const int ty = sy + di, tx = sx + dj;
            const bool inb = ((unsigned)ty < (unsigned)IH) && ((unsigned)tx < (unsigned)IW);
            const int pix = min(max(ty, 0), IH - 1) * IW + min(max(tx, 0), IW - 1);

            // lgn 4-vec f16: 16 nv-lanes read 16 consecutive 8B -> 128B segment
            H2x2 lgu = ((const H2x2*)ws)[(b * HWN + pix) * 16 + nv];
            __half2 lg01 = inb ? lgu.a : zero2;   // OOB unfold tap -> zero window
            __half2 lg23 = inb ? lgu.b : zero2;

            // d = g2(center) - g1(tap); g1 broadcasts within the 16-lane group
            const float2 g1 = ((const float2*)grid1)[b * HWN + pix];
            const float dxc = g2.x - g1.x;
            const float dyc = g2.y - g1.y;

            // x -> coefr o axis
            const float xf  = (dxc + 1.0f) * (0.5f * NSN) - 0.5f;
            const float xfl = floorf(xf);
            const float fx  = xf - xfl;
            const int   o0  = (int)xfl;
            const float wx0 = (o0 >= 0 && o0 <= NSN - 1) ? (1.0f - fx) : 0.0f;
            const float wx1 = (o0 + 1 >= 0 && o0 + 1 <= NSN - 1) ? fx : 0.0f;
            const int   o0c = min(max(o0, 0), NSN - 1);
            const int   o1c = min(max(o0 + 1, 0), NSN - 1);

            // y -> coefx n axis
            const float yf  = (dyc + 1.0f) * (0.5f * NSN) - 0.5f;
            const float yfl = floorf(yf);
            const float fy  = yf - yfl;
            const int   n0  = (int)yfl;
            const float wy0 = (n0 >= 0 && n0 <= NSN - 1) ? (1.0f - fy) : 0.0f;
            const float wy1 = (n0 + 1 >= 0 && n0 + 1 <= NSN - 1) ? fy : 0.0f;
            const int   n0c = min(max(n0, 0), NSN - 1);
            const int   n1c = min(max(n0 + 1, 0), NSN - 1);

            const __half2 wx0h = __floats2half2_rn(wx0, wx0);
            const __half2 wx1h = __floats2half2_rn(wx1, wx1);
            const __half2 wy0h = __floats2half2_rn(wy0, wy0);
            const __half2 wy1h = __floats2half2_rn(wy1, wy1);

            // blended C rows (packed f16): bl[q] over [k2*2 + lpair]
            const H2x4 c0a = sC[o0c * 49 + nv * 3 + 0];
            const H2x4 c0b = sC[o0c * 49 + nv * 3 + 1];
            const H2x4 c1a = sC[o1c * 49 + nv * 3 + 0];
            const H2x4 c1b = sC[o1c * 49 + nv * 3 + 1];
            __half2 bl[8];
            #pragma unroll
            for (int k = 0; k < 4; ++k) {
                bl[k]     = __hfma2(c0a.h[k], wx0h, __hmul2(c1a.h[k], wx1h));
                bl[4 + k] = __hfma2(c0b.h[k], wx0h, __hmul2(c1b.h[k], wx1h));
            }
            // v_k2 = C'(x) . lg   (reduce each half2 pair in f32)
            float vf[4];
            #pragma unroll
            for (int k2 = 0; k2 < 4; ++k2) {
                const __half2 sv = __hfma2(bl[2 * k2 + 1], lg23,
                                           __hmul2(bl[2 * k2], lg01));
                vf[k2] = __low2float(sv) + __high2float(sv);
            }
            const __half2 v01 = __floats2half2_rn(vf[0], vf[1]);
            const __half2 v23 = __floats2half2_rn(vf[2], vf[3]);

            // blended E rows, then acc_j += E'(y) . v  (f32 accumulate)
            const H2x4 e0a = sE[n0c * 49 + nv * 3 + 0];
            const H2x4 e0b = sE[n0c * 49 + nv * 3 + 1];
            const H2x4 e1a = sE[n1c * 49 + nv * 3 + 0];
            const H2x4 e1b = sE[n1c * 49 + nv * 3 + 1];
            __half2 eb[8];
            #pragma unroll
            for (int k = 0; k < 4; ++k) {
                eb[k]     = __hfma2(e0a.h[k], wy0h, __hmul2(e1a.h[k], wy1h));
                eb[4 + k] = __hfma2(e0b.h[k], wy0h, __hmul2(e1b.h[k], wy1h));
            }
            #pragma unroll
            for (int j = 0; j < 4; ++j) {
                const __half2 sa = __hfma2(eb[2 * j + 1], v23,
                                           __hmul2(eb[2 * j], v01));
                acc[j] += __low2float(sa) + __high2float(sa);
            }
        }
    }

    // ---- store-coalescing LDS round-trip: swap nv<->pg lane roles ----
    *(float4*)&sOut[pg][nv][0] = make_float4(acc[0], acc[1], acc[2], acc[3]);
    __syncthreads();
    {
        const int nv2 = t >> 4, pg2 = t & 15;
        #pragma unroll
        for (int j = 0; j < 4; ++j)
            out[(b * 64 + nv2 * 4 + j) * HWN + hwbase + pg2] = sOut[pg2][nv2][j];
    }
}

extern "C" void kernel_launch(void* const* d_in, const int* in_sizes, int n_in,
                              void* d_out, int out_size, void* d_ws, size_t ws_size,
                              hipStream_t stream) {
    const float* grid1 = (const float*)d_in[0];
    const float* grid2 = (const float*)d_in[1];
    const float* theta = (const float*)d_in[2];
    const float* lgn   = (const float*)d_in[3];
    const float* coefx = (const float*)d_in[4];
    const float* coefy = (const float*)d_in[5];
    const float* coefr = (const float*)d_in[6];
    float*       outp  = (float*)d_out;
    char*        ws    = (char*)d_ws;

    // prep: blocks 0..511 transpose lgn->f16; 512..543 E; 544..551 C repack
    hipLaunchKernelGGL(prep_kernel, dim3(552), dim3(256), 0, stream,
                       lgn, theta, coefx, coefy, coefr, ws);

    // main: 1024 blocks, 16 pixels x 16 nv per block
    hipLaunchKernelGGL(seprot_kernel, dim3(BB * 256), dim3(256), 0, stream,
                       grid1, grid2, ws, outp);
}

// Round 4
// 80.707 us; speedup vs baseline: 1.0267x; 1.0267x over previous
//
#include <hip/hip_runtime.h>
#include <hip/hip_fp16.h>
#include <cstdint>

// Problem constants
#define BB   4
#define IH   64
#define IW   64
#define HWN  4096
#define NVN  16
#define NSN  16

// dtypes (established R1-R3): all inputs f32, output f32.
//
// R5 post-mortem: 82.7us = ~63us fixed harness ws-fills + ~19.5us kernels.
// R6: LDS stride 49u (bank-phase rotation), store-coalescing LDS round-trip,
//     float4 transpose reads.
// R8 (first counters this session): total 82.86us; top-5 dispatches are ALL
//     256MiB harness ws-poison fills at 6.2-6.4 TB/s (78-81% HBM peak) --
//     fixed cost, not addressable. Kernel share ~20-38us.
// R9 theory: seprot is VALU-issue-bound; per-tap geometry (g1/g2 loads,
//     floor/clamp/weight math, ~30 VALU + 2 loads) was duplicated across the
//     16 nv lanes of each pixel. Change: 144-thread geometry pass (16 pix x
//     9 taps) before the staging barrier writes packed weights + pre-scaled
//     row offsets to LDS; main loop reads 16B+4B broadcasts instead.
//     `valid` (center OOB) and `inb` (tap OOB) are folded into wx weights
//     (zero weight => tap contributes exactly 0, matching reference
//     zero-padding; all operands finite). Main loop is now branch-free.
// R10: identical resubmit of R9 — R9 bench failed on GPU acquisition.
//     Re-audited index mapping + OOB weight-folds; no changes.
// Math identical to the verified separable factorization:
//   pred[j] = sum_taps (wy-blend E rows) . ((wx-blend C rows) . lgn4)

// ws layout (16B-aligned offsets):
//   lgnT f16 [b][hw][64ch]          : 4*4096*64*2  = 2 MiB
//   Ews  f16 [b][nv][n][j*4+k2]     : 4*16*16*16*2 = 32 KiB
//   Cws  f16 [nv][o][k2*4+l]        : 16*16*16*2   = 8 KiB
#define EWS_OFF  (BB*HWN*64*2)
#define CWS_OFF  (EWS_OFF + BB*NVN*NSN*16*2)

struct __align__(16) H2x4 { __half2 h[4]; };
struct __align__(8)  H2x2 { __half2 a, b; };
struct __align__(16) GeoA { __half2 wx01, wy01; ushort o0, o1, n0, n1; };

__global__ __launch_bounds__(256) void prep_kernel(
    const float* __restrict__ lgn, const float* __restrict__ theta,
    const float* __restrict__ coefx, const float* __restrict__ coefy,
    const float* __restrict__ coefr, char* __restrict__ ws)
{
    const int blk = blockIdx.x, t = threadIdx.x;
    if (blk < 512) {
        // transpose lgn [b][c][hw] f32 -> lgnT [b][hw][c] f16 (32-pixel tiles)
        __shared__ float tile[64][33];   // stride 33: pack-read 2-way max
        const int b      = blk >> 7;
        const int hwbase = (blk & 127) << 5;
        const float* src = lgn + (size_t)b * (64 * HWN) + hwbase;
        const int x4 = t & 7;        // float4 col: 8 x 16B = 32 floats
        const int c0 = t >> 3;       // 32 rows per iter
        #pragma unroll
        for (int i = 0; i < 2; ++i) {
            const int c = c0 + i * 32;
            const float4 v = *(const float4*)&src[c * HWN + x4 * 4];
            tile[c][x4 * 4 + 0] = v.x;
            tile[c][x4 * 4 + 1] = v.y;
            tile[c][x4 * 4 + 2] = v.z;
            tile[c][x4 * 4 + 3] = v.w;
        }
        __syncthreads();
        __half2* dst = (__half2*)ws + (size_t)b * (HWN * 32) + (size_t)hwbase * 32;
        const int cp = t & 31, hw0 = t >> 5;
        #pragma unroll
        for (int i = 0; i < 4; ++i) {
            const int hw = hw0 + i * 8;
            dst[hw * 32 + cp] =
                __floats2half2_rn(tile[2 * cp][hw], tile[2 * cp + 1][hw]);
        }
    } else if (blk < 544) {
        // E[b][nv][n][j*4+k2] = sum_k1 coefx[nv,j,k1,n] *
        //   (wz0*coefy[nv,k1,k2,m0c] + wz1*coefy[nv,k1,k2,m1c]);  half2 pairs
        const int p  = (blk - 512) * 256 + t;        // 8192 half2 pairs
        const int b  = p >> 11, nv = (p >> 7) & 15, n = (p >> 3) & 15, q = p & 7;
        const float th  = theta[b] * 0.31830988618379067154f;   // theta/pi
        const float zf  = (th + 1.0f) * 8.0f - 0.5f;
        const float zfl = floorf(zf);
        const float fz  = zf - zfl;
        const int   m0  = (int)zfl;
        const float wz0 = (m0 >= 0 && m0 <= 15) ? (1.0f - fz) : 0.0f;
        const float wz1 = (m0 + 1 >= 0 && m0 + 1 <= 15) ? fz : 0.0f;
        const int   m0c = min(max(m0, 0), 15), m1c = min(max(m0 + 1, 0), 15);
        float ev[2];
        #pragma unroll
        for (int s = 0; s < 2; ++s) {
            const int idx = 2 * q + s, j = idx >> 2, k2 = idx & 3;
            float e = 0.0f;
            #pragma unroll
            for (int k1 = 0; k1 < 4; ++k1) {
                const float a  = coefx[nv * 256 + (j * 4 + k1) * 16 + n];
                const float bm = wz0 * coefy[nv * 256 + (k1 * 4 + k2) * 16 + m0c]
                               + wz1 * coefy[nv * 256 + (k1 * 4 + k2) * 16 + m1c];
                e += a * bm;
            }
            ev[s] = e;
        }
        ((__half2*)(ws + EWS_OFF))[p] = __floats2half2_rn(ev[0], ev[1]);
    } else {
        // C repack: Cws[nv][o][k2*4+l] = coefr[nv,k2,l,o];  half2 pairs
        const int p = (blk - 544) * 256 + t;          // 2048 half2 pairs
        if (p < 2048) {
            const int nv = p >> 7, o = (p >> 3) & 15, q = p & 7;
            const float c0 = coefr[nv * 256 + (2 * q + 0) * 16 + o];
            const float c1 = coefr[nv * 256 + (2 * q + 1) * 16 + o];
            ((__half2*)(ws + CWS_OFF))[p] = __floats2half2_rn(c0, c1);
        }
    }
}

// LDS layout for C/E: 16B units, unit(nv,o,u) = o*49 + nv*3 + u (u=0,1 data).
// Row stride 49u = 196 words === 4 mod 32 -> rows rotate bank phase.
// Geo entries: 16B stride; 4 pixel-groups per wave read rows 36 words apart
// (=== 4 mod 32) -> 4 disjoint bank spans; 16-lane same-address broadcast.
__global__ __launch_bounds__(256) void seprot_kernel(
    const float* __restrict__ grid1,
    const float* __restrict__ grid2,
    const char*  __restrict__ ws,
    float* __restrict__ out)
{
    __shared__ H2x4 sC[16 * 49];        // 12.25 KiB
    __shared__ H2x4 sE[16 * 49];        // 12.25 KiB
    __shared__ float sOut[16][17][4];   // 4.25 KiB store-coalescing stage
    __shared__ GeoA sGeoA[16 * 9];      // 2.25 KiB per-(pixel,tap) geometry
    __shared__ int  sGeoP[16 * 9];      // 576 B lgnT base offsets

    const int t   = threadIdx.x;
    const int blk = blockIdx.x;
    const int b      = blk >> 8;             // block-uniform
    const int hwbase = (blk & 255) << 4;     // 16 pixels per block
    const int pg = t >> 4;                   // pixel in block (0..15)
    const int nv = t & 15;                   // lane-group = 16 nv of one pixel

    // ---- stage C + E[b] (coalesced copy, padding applied here) ----
    {
        const H2x4* Cw = (const H2x4*)(ws + CWS_OFF);
        const H2x4* Ew = (const H2x4*)(ws + EWS_OFF) + b * 512;
        #pragma unroll
        for (int k = 0; k < 2; ++k) {
            const int i   = t + k * 256;                 // 512 units each
            const int wnv = i >> 5, wo = (i >> 1) & 15, wu = i & 1;
            const int du  = wo * 49 + wnv * 3 + wu;
            sC[du] = Cw[i];
            sE[du] = Ew[i];
        }
    }

    // ---- geometry pass: one thread per (pixel, tap); weights fold OOB ----
    if (t < 144) {
        const int pix_i = t / 9;             // 0..15
        const int tap   = t - pix_i * 9;     // 0..8
        const float2 g2 = ((const float2*)grid2)[b * HWN + hwbase + pix_i];
        const float sxf = rintf((g2.x + 1.0f) * (0.5f * IW) - 0.5f);
        const float syf = rintf((g2.y + 1.0f) * (0.5f * IH) - 0.5f);
        const bool valid = (sxf >= 0.0f) && (sxf <= (float)(IW - 1)) &&
                           (syf >= 0.0f) && (syf <= (float)(IH - 1));
        const int sx = (int)sxf, sy = (int)syf;
        const int ty = sy + tap / 3 - 1, tx = sx + tap % 3 - 1;
        const bool inb = valid &&
                         ((unsigned)ty < (unsigned)IH) && ((unsigned)tx < (unsigned)IW);
        const int pix = min(max(ty, 0), IH - 1) * IW + min(max(tx, 0), IW - 1);

        const float2 g1 = ((const float2*)grid1)[b * HWN + pix];
        const float dxc = g2.x - g1.x;
        const float dyc = g2.y - g1.y;

        // x -> coefr o axis
        const float xf  = (dxc + 1.0f) * (0.5f * NSN) - 0.5f;
        const float xfl = floorf(xf);
        const float fx  = xf - xfl;
        const int   o0  = (int)xfl;
        float wx0 = (o0 >= 0 && o0 <= NSN - 1) ? (1.0f - fx) : 0.0f;
        float wx1 = (o0 + 1 >= 0 && o0 + 1 <= NSN - 1) ? fx : 0.0f;
        const int o0c = min(max(o0, 0), NSN - 1);
        const int o1c = min(max(o0 + 1, 0), NSN - 1);

        // y -> coefx n axis
        const float yf  = (dyc + 1.0f) * (0.5f * NSN) - 0.5f;
        const float yfl = floorf(yf);
        const float fy  = yf - yfl;
        const int   n0  = (int)yfl;
        const float wy0 = (n0 >= 0 && n0 <= NSN - 1) ? (1.0f - fy) : 0.0f;
        const float wy1 = (n0 + 1 >= 0 && n0 + 1 <= NSN - 1) ? fy : 0.0f;
        const int n0c = min(max(n0, 0), NSN - 1);
        const int n1c = min(max(n0 + 1, 0), NSN - 1);

        // fold center-valid + tap-in-bounds into the wx weights:
        // zero weight -> this tap contributes exactly 0 (reference zero-pad)
        const float kz = inb ? 1.0f : 0.0f;
        GeoA ga;
        ga.wx01 = __floats2half2_rn(wx0 * kz, wx1 * kz);
        ga.wy01 = __floats2half2_rn(wy0, wy1);
        ga.o0 = (ushort)(o0c * 49);
        ga.o1 = (ushort)(o1c * 49);
        ga.n0 = (ushort)(n0c * 49);
        ga.n1 = (ushort)(n1c * 49);
        sGeoA[t] = ga;
        sGeoP[t] = (b * HWN + pix) * 16;
    }
    __syncthreads();

    float acc[4] = {0.0f, 0.0f, 0.0f, 0.0f};
    const int nv3   = nv * 3;
    const int gbase = pg * 9;

    #pragma unroll
    for (int tap = 0; tap < 9; ++tap) {
        const GeoA ga  = sGeoA[gbase + tap];
        const int lgoff = sGeoP[gbase + tap];

        // lgn 4-vec f16: 16 nv-lanes read 16 consecutive 8B -> 128B segment
        const H2x2 lgu = ((const H2x2*)ws)[lgoff + nv];

        const __half2 wx0h = __low2half2(ga.wx01);
        const __half2 wx1h = __high2half2(ga.wx01);
        const __half2 wy0h = __low2half2(ga.wy01);
        const __half2 wy1h = __high2half2(ga.wy01);

        // blended C rows (packed f16): bl[q] over [k2*2 + lpair]
        const H2x4 c0a = sC[ga.o0 + nv3 + 0];
        const H2x4 c0b = sC[ga.o0 + nv3 + 1];
        const H2x4 c1a = sC[ga.o1 + nv3 + 0];
        const H2x4 c1b = sC[ga.o1 + nv3 + 1];
        __half2 bl[8];
        #pragma unroll
        for (int k = 0; k < 4; ++k) {
            bl[k]     = __hfma2(c0a.h[k], wx0h, __hmul2(c1a.h[k], wx1h));
            bl[4 + k] = __hfma2(c0b.h[k], wx0h, __hmul2(c1b.h[k], wx1h));
        }
        // v_k2 = C'(x) . lg   (reduce each half2 pair in f32)
        float vf[4];
        #pragma unroll
        for (int k2 = 0; k2 < 4; ++k2) {
            const __half2 sv = __hfma2(bl[2 * k2 + 1], lgu.b,
                                       __hmul2(bl[2 * k2], lgu.a));
            vf[k2] = __low2float(sv) + __high2float(sv);
        }
        const __half2 v01 = __floats2half2_rn(vf[0], vf[1]);
        const __half2 v23 = __floats2half2_rn(vf[2], vf[3]);

        // blended E rows, then acc_j += E'(y) . v  (f32 accumulate)
        const H2x4 e0a = sE[ga.n0 + nv3 + 0];
        const H2x4 e0b = sE[ga.n0 + nv3 + 1];
        const H2x4 e1a = sE[ga.n1 + nv3 + 0];
        const H2x4 e1b = sE[ga.n1 + nv3 + 1];
        __half2 eb[8];
        #pragma unroll
        for (int k = 0; k < 4; ++k) {
            eb[k]     = __hfma2(e0a.h[k], wy0h, __hmul2(e1a.h[k], wy1h));
            eb[4 + k] = __hfma2(e0b.h[k], wy0h, __hmul2(e1b.h[k], wy1h));
        }
        #pragma unroll
        for (int j = 0; j < 4; ++j) {
            const __half2 sa = __hfma2(eb[2 * j + 1], v23,
                                       __hmul2(eb[2 * j], v01));
            acc[j] += __low2float(sa) + __high2float(sa);
        }
    }

    // ---- store-coalescing LDS round-trip: swap nv<->pg lane roles ----
    *(float4*)&sOut[pg][nv][0] = make_float4(acc[0], acc[1], acc[2], acc[3]);
    __syncthreads();
    {
        const int nv2 = t >> 4, pg2 = t & 15;
        #pragma unroll
        for (int j = 0; j < 4; ++j)
            out[(b * 64 + nv2 * 4 + j) * HWN + hwbase + pg2] = sOut[pg2][nv2][j];
    }
}

extern "C" void kernel_launch(void* const* d_in, const int* in_sizes, int n_in,
                              void* d_out, int out_size, void* d_ws, size_t ws_size,
                              hipStream_t stream) {
    const float* grid1 = (const float*)d_in[0];
    const float* grid2 = (const float*)d_in[1];
    const float* theta = (const float*)d_in[2];
    const float* lgn   = (const float*)d_in[3];
    const float* coefx = (const float*)d_in[4];
    const float* coefy = (const float*)d_in[5];
    const float* coefr = (const float*)d_in[6];
    float*       outp  = (float*)d_out;
    char*        ws    = (char*)d_ws;

    // prep: blocks 0..511 transpose lgn->f16; 512..543 E; 544..551 C repack
    hipLaunchKernelGGL(prep_kernel, dim3(552), dim3(256), 0, stream,
                       lgn, theta, coefx, coefy, coefr, ws);

    // main: 1024 blocks, 16 pixels x 16 nv per block
    hipLaunchKernelGGL(seprot_kernel, dim3(BB * 256), dim3(256), 0, stream,
                       grid1, grid2, ws, outp);
}

// Round 13
// 80.452 us; speedup vs baseline: 1.0299x; 1.0032x over previous
//
#include <hip/hip_runtime.h>
#include <hip/hip_fp16.h>
#include <cstdint>

// Problem constants
#define BB   4
#define IH   64
#define IW   64
#define HWN  4096
#define NVN  16
#define NSN  16

// dtypes (established R1-R3): all inputs f32, output f32.
//
// R8: total 82.86us; top-5 = 256MiB harness poison fills at ~80% HBM peak
//     (fixed, not addressable). Addressable ~17-20us (prep + gap + seprot).
// R9/R10 (WIN, -2.15us -> 80.71): geometry de-dup into 144-thread LDS pass;
//     OOB folded into wx weights (exact zero contribution). absmax unchanged.
// R11 (FAILED, absmax 1.66e-2): cooperative prep+seprot fusion. grid.sync()
//     no-oped under the harness's GRAPH CAPTURE (cooperative launch degrades
//     to plain node). RULE: no grid-wide sync here; deps stay cross-dispatch.
// R12: revert to R10 two-kernel structure + v_dot2_f32_f16
//     (__builtin_amdgcn_fdot2) for the C'(x).lg and E'(y).v dot stages:
//     1 inst per half2 pair w/ f32 accum (replaces hfma2+cvt+add chains,
//     ~20-25% of seprot VALU), precision same-or-better.
//     launch_bounds(256,5) occupancy idea REJECTED: grid is exactly 1024
//     blocks = 4/CU x 256 CU; capacity 5 adds no resident waves.
// R13-R19: identical resubmits — benches failed on infra (GPU acquisition
//     timeouts, 2x container failure). fdot2 candidate still unmeasured.
// Math: pred[j] = sum_taps (wy-blend E rows) . ((wx-blend C rows) . lgn4)

// ws layout (16B-aligned offsets):
//   lgnT f16 [b][hw][64ch]          : 4*4096*64*2  = 2 MiB
//   Ews  f16 [b][nv][n][j*4+k2]     : 4*16*16*16*2 = 32 KiB
//   Cws  f16 [nv][o][k2*4+l]        : 16*16*16*2   = 8 KiB
#define EWS_OFF  (BB*HWN*64*2)
#define CWS_OFF  (EWS_OFF + BB*NVN*NSN*16*2)

struct __align__(16) H2x4 { __half2 h[4]; };
struct __align__(8)  H2x2 { __half2 a, b; };
struct __align__(16) GeoA { __half2 wx01, wy01; ushort o0, o1, n0, n1; };

// f32 <- a.x*b.x + a.y*b.y + c  (one v_dot2_f32_f16; f32 accumulate)
static __device__ __forceinline__ float fdot2(__half2 a, __half2 b, float c) {
#if __has_builtin(__builtin_amdgcn_fdot2)
    typedef _Float16 __attribute__((ext_vector_type(2))) v2h;
    return __builtin_amdgcn_fdot2(__builtin_bit_cast(v2h, a),
                                  __builtin_bit_cast(v2h, b), c, false);
#else
    const __half2 p = __hmul2(a, b);
    return c + __low2float(p) + __high2float(p);
#endif
}

__global__ __launch_bounds__(256) void prep_kernel(
    const float* __restrict__ lgn, const float* __restrict__ theta,
    const float* __restrict__ coefx, const float* __restrict__ coefy,
    const float* __restrict__ coefr, char* __restrict__ ws)
{
    const int blk = blockIdx.x, t = threadIdx.x;
    if (blk < 512) {
        // transpose lgn [b][c][hw] f32 -> lgnT [b][hw][c] f16 (32-pixel tiles)
        __shared__ float tile[64][33];   // stride 33: pack-read 2-way max
        const int b      = blk >> 7;
        const int hwbase = (blk & 127) << 5;
        const float* src = lgn + (size_t)b * (64 * HWN) + hwbase;
        const int x4 = t & 7;        // float4 col: 8 x 16B = 32 floats
        const int c0 = t >> 3;       // 32 rows per iter
        #pragma unroll
        for (int i = 0; i < 2; ++i) {
            const int c = c0 + i * 32;
            const float4 v = *(const float4*)&src[c * HWN + x4 * 4];
            tile[c][x4 * 4 + 0] = v.x;
            tile[c][x4 * 4 + 1] = v.y;
            tile[c][x4 * 4 + 2] = v.z;
            tile[c][x4 * 4 + 3] = v.w;
        }
        __syncthreads();
        __half2* dst = (__half2*)ws + (size_t)b * (HWN * 32) + (size_t)hwbase * 32;
        const int cp = t & 31, hw0 = t >> 5;
        #pragma unroll
        for (int i = 0; i < 4; ++i) {
            const int hw = hw0 + i * 8;
            dst[hw * 32 + cp] =
                __floats2half2_rn(tile[2 * cp][hw], tile[2 * cp + 1][hw]);
        }
    } else if (blk < 544) {
        // E[b][nv][n][j*4+k2] = sum_k1 coefx[nv,j,k1,n] *
        //   (wz0*coefy[nv,k1,k2,m0c] + wz1*coefy[nv,k1,k2,m1c]);  half2 pairs
        const int p  = (blk - 512) * 256 + t;        // 8192 half2 pairs
        const int b  = p >> 11, nv = (p >> 7) & 15, n = (p >> 3) & 15, q = p & 7;
        const float th  = theta[b] * 0.31830988618379067154f;   // theta/pi
        const float zf  = (th + 1.0f) * 8.0f - 0.5f;
        const float zfl = floorf(zf);
        const float fz  = zf - zfl;
        const int   m0  = (int)zfl;
        const float wz0 = (m0 >= 0 && m0 <= 15) ? (1.0f - fz) : 0.0f;
        const float wz1 = (m0 + 1 >= 0 && m0 + 1 <= 15) ? fz : 0.0f;
        const int   m0c = min(max(m0, 0), 15), m1c = min(max(m0 + 1, 0), 15);
        float ev[2];
        #pragma unroll
        for (int s = 0; s < 2; ++s) {
            const int idx = 2 * q + s, j = idx >> 2, k2 = idx & 3;
            float e = 0.0f;
            #pragma unroll
            for (int k1 = 0; k1 < 4; ++k1) {
                const float a  = coefx[nv * 256 + (j * 4 + k1) * 16 + n];
                const float bm = wz0 * coefy[nv * 256 + (k1 * 4 + k2) * 16 + m0c]
                               + wz1 * coefy[nv * 256 + (k1 * 4 + k2) * 16 + m1c];
                e += a * bm;
            }
            ev[s] = e;
        }
        ((__half2*)(ws + EWS_OFF))[p] = __floats2half2_rn(ev[0], ev[1]);
    } else {
        // C repack: Cws[nv][o][k2*4+l] = coefr[nv,k2,l,o];  half2 pairs
        const int p = (blk - 544) * 256 + t;          // 2048 half2 pairs
        if (p < 2048) {
            const int nv = p >> 7, o = (p >> 3) & 15, q = p & 7;
            const float c0 = coefr[nv * 256 + (2 * q + 0) * 16 + o];
            const float c1 = coefr[nv * 256 + (2 * q + 1) * 16 + o];
            ((__half2*)(ws + CWS_OFF))[p] = __floats2half2_rn(c0, c1);
        }
    }
}

// LDS layout for C/E: 16B units, unit(nv,o,u) = o*49 + nv*3 + u (u=0,1 data).
// Row stride 49u = 196 words === 4 mod 32 -> rows rotate bank phase.
// Geo entries: 16B stride; 4 pixel-groups per wave read rows 36 words apart
// (=== 4 mod 32) -> 4 disjoint bank spans; 16-lane same-address broadcast.
__global__ __launch_bounds__(256) void seprot_kernel(
    const float* __restrict__ grid1,
    const float* __restrict__ grid2,
    const char*  __restrict__ ws,
    float* __restrict__ out)
{
    __shared__ H2x4 sC[16 * 49];        // 12.25 KiB
    __shared__ H2x4 sE[16 * 49];        // 12.25 KiB
    __shared__ float sOut[16][17][4];   // 4.25 KiB store-coalescing stage
    __shared__ GeoA sGeoA[16 * 9];      // 2.25 KiB per-(pixel,tap) geometry
    __shared__ int  sGeoP[16 * 9];      // 576 B lgnT base offsets

    const int t   = threadIdx.x;
    const int blk = blockIdx.x;
    const int b      = blk >> 8;             // block-uniform
    const int hwbase = (blk & 255) << 4;     // 16 pixels per block
    const int pg = t >> 4;                   // pixel in block (0..15)
    const int nv = t & 15;                   // lane-group = 16 nv of one pixel

    // ---- stage C + E[b] (coalesced copy, padding applied here) ----
    {
        const H2x4* Cw = (const H2x4*)(ws + CWS_OFF);
        const H2x4* Ew = (const H2x4*)(ws + EWS_OFF) + b * 512;
        #pragma unroll
        for (int k = 0; k < 2; ++k) {
            const int i   = t + k * 256;                 // 512 units each
            const int wnv = i >> 5, wo = (i >> 1) & 15, wu = i & 1;
            const int du  = wo * 49 + wnv * 3 + wu;
            sC[du] = Cw[i];
            sE[du] = Ew[i];
        }
    }

    // ---- geometry pass: one thread per (pixel, tap); weights fold OOB ----
    if (t < 144) {
        const int pix_i = t / 9;             // 0..15
        const int tap   = t - pix_i * 9;     // 0..8
        const float2 g2 = ((const float2*)grid2)[b * HWN + hwbase + pix_i];
        const float sxf = rintf((g2.x + 1.0f) * (0.5f * IW) - 0.5f);
        const float syf = rintf((g2.y + 1.0f) * (0.5f * IH) - 0.5f);
        const bool valid = (sxf >= 0.0f) && (sxf <= (float)(IW - 1)) &&
                           (syf >= 0.0f) && (syf <= (float)(IH - 1));
        const int sx = (int)sxf, sy = (int)syf;
        const int ty = sy + tap / 3 - 1, tx = sx + tap % 3 - 1;
        const bool inb = valid &&
                         ((unsigned)ty < (unsigned)IH) && ((unsigned)tx < (unsigned)IW);
        const int pix = min(max(ty, 0), IH - 1) * IW + min(max(tx, 0), IW - 1);

        const float2 g1 = ((const float2*)grid1)[b * HWN + pix];
        const float dxc = g2.x - g1.x;
        const float dyc = g2.y - g1.y;

        // x -> coefr o axis
        const float xf  = (dxc + 1.0f) * (0.5f * NSN) - 0.5f;
        const float xfl = floorf(xf);
        const float fx  = xf - xfl;
        const int   o0  = (int)xfl;
        const float wx0 = (o0 >= 0 && o0 <= NSN - 1) ? (1.0f - fx) : 0.0f;
        const float wx1 = (o0 + 1 >= 0 && o0 + 1 <= NSN - 1) ? fx : 0.0f;
        const int o0c = min(max(o0, 0), NSN - 1);
        const int o1c = min(max(o0 + 1, 0), NSN - 1);

        // y -> coefx n axis
        const float yf  = (dyc + 1.0f) * (0.5f * NSN) - 0.5f;
        const float yfl = floorf(yf);
        const float fy  = yf - yfl;
        const int   n0  = (int)yfl;
        const float wy0 = (n0 >= 0 && n0 <= NSN - 1) ? (1.0f - fy) : 0.0f;
        const float wy1 = (n0 + 1 >= 0 && n0 + 1 <= NSN - 1) ? fy : 0.0f;
        const int n0c = min(max(n0, 0), NSN - 1);
        const int n1c = min(max(n0 + 1, 0), NSN - 1);

        // fold center-valid + tap-in-bounds into the wx weights:
        // zero weight -> this tap contributes exactly 0 (reference zero-pad)
        const float kz = inb ? 1.0f : 0.0f;
        GeoA ga;
        ga.wx01 = __floats2half2_rn(wx0 * kz, wx1 * kz);
        ga.wy01 = __floats2half2_rn(wy0, wy1);
        ga.o0 = (ushort)(o0c * 49);
        ga.o1 = (ushort)(o1c * 49);
        ga.n0 = (ushort)(n0c * 49);
        ga.n1 = (ushort)(n1c * 49);
        sGeoA[t] = ga;
        sGeoP[t] = (b * HWN + pix) * 16;
    }
    __syncthreads();

    float acc[4] = {0.0f, 0.0f, 0.0f, 0.0f};
    const int nv3   = nv * 3;
    const int gbase = pg * 9;

    #pragma unroll
    for (int tap = 0; tap < 9; ++tap) {
        const GeoA ga   = sGeoA[gbase + tap];
        const int lgoff = sGeoP[gbase + tap];

        // lgn 4-vec f16: 16 nv-lanes read 16 consecutive 8B -> 128B segment
        const H2x2 lgu = ((const H2x2*)ws)[lgoff + nv];

        const __half2 wx0h = __low2half2(ga.wx01);
        const __half2 wx1h = __high2half2(ga.wx01);
        const __half2 wy0h = __low2half2(ga.wy01);
        const __half2 wy1h = __high2half2(ga.wy01);

        // blended C rows (packed f16): bl[q] over [k2*2 + lpair]
        const H2x4 c0a = sC[ga.o0 + nv3 + 0];
        const H2x4 c0b = sC[ga.o0 + nv3 + 1];
        const H2x4 c1a = sC[ga.o1 + nv3 + 0];
        const H2x4 c1b = sC[ga.o1 + nv3 + 1];
        __half2 bl[8];
        #pragma unroll
        for (int k = 0; k < 4; ++k) {
            bl[k]     = __hfma2(c0a.h[k], wx0h, __hmul2(c1a.h[k], wx1h));
            bl[4 + k] = __hfma2(c0b.h[k], wx0h, __hmul2(c1b.h[k], wx1h));
        }
        // v_k2 = C'(x) . lg   (v_dot2_f32_f16: f32 accumulate)
        float vf[4];
        #pragma unroll
        for (int k2 = 0; k2 < 4; ++k2)
            vf[k2] = fdot2(bl[2 * k2 + 1], lgu.b, fdot2(bl[2 * k2], lgu.a, 0.0f));
        const __half2 v01 = __floats2half2_rn(vf[0], vf[1]);
        const __half2 v23 = __floats2half2_rn(vf[2], vf[3]);

        // blended E rows, then acc_j += E'(y) . v  (f32 dot accumulate)
        const H2x4 e0a = sE[ga.n0 + nv3 + 0];
        const H2x4 e0b = sE[ga.n0 + nv3 + 1];
        const H2x4 e1a = sE[ga.n1 + nv3 + 0];
        const H2x4 e1b = sE[ga.n1 + nv3 + 1];
        __half2 eb[8];
        #pragma unroll
        for (int k = 0; k < 4; ++k) {
            eb[k]     = __hfma2(e0a.h[k], wy0h, __hmul2(e1a.h[k], wy1h));
            eb[4 + k] = __hfma2(e0b.h[k], wy0h, __hmul2(e1b.h[k], wy1h));
        }
        #pragma unroll
        for (int j = 0; j < 4; ++j)
            acc[j] = fdot2(eb[2 * j + 1], v23, fdot2(eb[2 * j], v01, acc[j]));
    }

    // ---- store-coalescing LDS round-trip: swap nv<->pg lane roles ----
    *(float4*)&sOut[pg][nv][0] = make_float4(acc[0], acc[1], acc[2], acc[3]);
    __syncthreads();
    {
        const int nv2 = t >> 4, pg2 = t & 15;
        #pragma unroll
        for (int j = 0; j < 4; ++j)
            out[(b * 64 + nv2 * 4 + j) * HWN + hwbase + pg2] = sOut[pg2][nv2][j];
    }
}

extern "C" void kernel_launch(void* const* d_in, const int* in_sizes, int n_in,
                              void* d_out, int out_size, void* d_ws, size_t ws_size,
                              hipStream_t stream) {
    const float* grid1 = (const float*)d_in[0];
    const float* grid2 = (const float*)d_in[1];
    const float* theta = (const float*)d_in[2];
    const float* lgn   = (const float*)d_in[3];
    const float* coefx = (const float*)d_in[4];
    const float* coefy = (const float*)d_in[5];
    const float* coefr = (const float*)d_in[6];
    float*       outp  = (float*)d_out;
    char*        ws    = (char*)d_ws;

    // prep: blocks 0..511 transpose lgn->f16; 512..543 E; 544..551 C repack
    hipLaunchKernelGGL(prep_kernel, dim3(552), dim3(256), 0, stream,
                       lgn, theta, coefx, coefy, coefr, ws);

    // main: 1024 blocks, 16 pixels x 16 nv per block
    hipLaunchKernelGGL(seprot_kernel, dim3(BB * 256), dim3(256), 0, stream,
                       grid1, grid2, ws, outp);
}